// Round 2
// baseline (351.417 us; speedup 1.0000x reference)
//
#include <hip/hip_runtime.h>

// Problem constants (ConvHex): B=256, C_IN=64, C_OUT=128, H=1039, K=6
// Dtypes (per reference + harness contract): x, weights, bias, out = fp32;
// neighbors = int32. Compute uses bf16 MFMA (inputs converted on the fly);
// threshold 3.375e-2 (2% of max|ref|) comfortably covers bf16 rounding.
#define BATCH 256
#define CIN   64
#define COUT  128
#define HEX   1039
#define KNB   6
#define KDIM  448          // CIN * (KNB + 1)
#define BN    64           // h per block in GEMM
#define NTH   17           // ceil(HEX / BN)
#define BKP   456          // padded LDS row stride (448 + 8) — keeps 16B align, breaks pow2

typedef __attribute__((ext_vector_type(8))) short bf16x8;   // 8 bf16 = 4 VGPRs
typedef __attribute__((ext_vector_type(4))) float f32x4;

__device__ __forceinline__ unsigned short f2bf(float f) {
    unsigned int u = __builtin_bit_cast(unsigned int, f);
    u += 0x7fffu + ((u >> 16) & 1);          // RTNE
    return (unsigned short)(u >> 16);
}

// ---------------------------------------------------------------------------
// Kernel 1 (fast path only): x[b][c][h] fp32 -> xt[b][h][c] bf16.
// Makes each neighbor-gather a contiguous 128B row (64 c * 2B).
__global__ __launch_bounds__(256) void k_transpose(const float* __restrict__ x,
                                                   unsigned short* __restrict__ xt) {
    __shared__ unsigned short tile[64][65];
    int b  = blockIdx.x / NTH;
    int ht = blockIdx.x % NTH;
    int h0 = ht * 64;
    int tid = threadIdx.x;

    const float* xb = x + (size_t)b * CIN * HEX;
    int hi = tid & 63;            // h-in-tile, coalesced read dim
    int ci = tid >> 6;            // 0..3
    for (int cc = ci; cc < 64; cc += 4) {
        int h = h0 + hi;
        tile[cc][hi] = (h < HEX) ? f2bf(xb[(size_t)cc * HEX + h]) : (unsigned short)0;
    }
    __syncthreads();

    unsigned short* xtb = xt + (size_t)b * HEX * CIN;
    int co = (tid & 15) * 4;      // 4 consecutive c per thread -> ushort4 store
    int hj = tid >> 4;            // 0..15
    for (int hh = hj; hh < 64; hh += 16) {
        int h = h0 + hh;
        if (h < HEX) {
            ushort4 v;
            v.x = tile[co + 0][hh];
            v.y = tile[co + 1][hh];
            v.z = tile[co + 2][hh];
            v.w = tile[co + 3][hh];
            *(ushort4*)(xtb + (size_t)h * CIN + co) = v;
        }
    }
}

// ---------------------------------------------------------------------------
// Kernel 2: pack [Wc | Wn] (fp32) into bf16 MFMA A-fragment lane order.
// wf element e = ((kb*8 + mtile)*64 + lane)*8 + j :
//   o  = mtile*16 + (lane&15)
//   kd = kb*32 + (lane>>4)*8 + j,  kd = jn*64 + c  (jn==0 -> center)
__global__ __launch_bounds__(256) void k_packw(const float* __restrict__ wc,
                                               const float* __restrict__ wn,
                                               unsigned short* __restrict__ wf) {
    int e    = blockIdx.x * 256 + threadIdx.x;   // 0 .. 57343
    int j    = e & 7;
    int lane = (e >> 3) & 63;
    int mt   = (e >> 9) & 7;
    int kb   = e >> 12;                          // 0..13
    int o  = mt * 16 + (lane & 15);
    int kd = kb * 32 + (lane >> 4) * 8 + j;
    int jn = kd >> 6;
    int c  = kd & 63;
    float v = (jn == 0) ? wc[o * CIN + c]
                        : wn[(o * CIN + c) * KNB + (jn - 1)];
    wf[e] = f2bf(v);
}

// ---------------------------------------------------------------------------
// Kernel 3: inv_tv[h] = 1 / (1 + #valid neighbors)
__global__ __launch_bounds__(256) void k_invtv(const int* __restrict__ nb,
                                               float* __restrict__ invtv) {
    int h = blockIdx.x * 256 + threadIdx.x;
    if (h < HEX) {
        int cnt = 1;
        #pragma unroll
        for (int k = 0; k < KNB; ++k) cnt += (nb[h * KNB + k] >= 0) ? 1 : 0;
        invtv[h] = 1.0f / (float)cnt;
    }
}

// ---------------------------------------------------------------------------
// Kernel 4: gathered GEMM. Block = (b, 64-h tile); 4 waves.
// B-tile gathered to LDS once (1 barrier), A read lane-linear from global wf.
// Wave w computes o in [w*32, w*32+32) x all 64 h: 2 m-frags x 4 n-frags.
// If xt == nullptr (workspace too small), gathers scalar fp32 from x directly.
__global__ __launch_bounds__(256) void k_gemm(const float* __restrict__ x,
                                              const unsigned short* __restrict__ xt,
                                              const unsigned short* __restrict__ wf,
                                              const int* __restrict__ nb,
                                              const float* __restrict__ invtv,
                                              const float* __restrict__ bias,
                                              float* __restrict__ out) {
    __shared__ __align__(16) unsigned short Bs[BN * BKP];   // 58368 B

    int ht = blockIdx.x % NTH;
    int b  = blockIdx.x / NTH;
    int h0 = ht * BN;
    int tid = threadIdx.x;

    // ---- stage B: Bs[n][jn*64 + c] = bf16(x[b][c][hex(n,jn)]), zeros where invalid
    if (xt) {
        // fast path: 16B rows from bf16 transposed copy
        const unsigned short* xtb = xt + (size_t)b * (HEX * CIN);
        int lane8 = tid & 7;                 // 16B chunk within a 128B row
        int p0    = tid >> 3;                // 0..31
        for (int p = p0; p < KDIM; p += 32) { // p = jn*64 + n
            int jn = p >> 6;
            int n  = p & 63;
            int h  = h0 + n;
            int g  = -1;
            if (h < HEX) g = (jn == 0) ? h : nb[h * KNB + (jn - 1)];
            bf16x8 v = {};
            if (g >= 0) v = *(const bf16x8*)(xtb + (size_t)g * CIN + lane8 * 8);
            *(bf16x8*)(&Bs[n * BKP + jn * 64 + lane8 * 8]) = v;
        }
    } else {
        // fallback: scalar fp32 gather straight from x (one wave per row, c=lane)
        const float* xb = x + (size_t)b * (CIN * HEX);
        int c  = tid & 63;
        int p0 = tid >> 6;                   // 0..3 (wave id)
        for (int p = p0; p < KDIM; p += 4) { // p = jn*64 + n
            int jn = p >> 6;
            int n  = p & 63;
            int h  = h0 + n;
            int g  = -1;
            if (h < HEX) g = (jn == 0) ? h : nb[h * KNB + (jn - 1)];
            float v = (g >= 0) ? xb[(size_t)c * HEX + g] : 0.0f;
            Bs[n * BKP + jn * 64 + c] = f2bf(v);
        }
    }
    __syncthreads();

    int wv   = tid >> 6;        // wave 0..3
    int lane = tid & 63;
    int quad = lane >> 4;
    int l16  = lane & 15;

    f32x4 acc0[4] = {};         // m-frag 0 (o = wv*32 + 0..15), 4 n-frags
    f32x4 acc1[4] = {};         // m-frag 1 (o = wv*32 + 16..31)

    const bf16x8* wfv = (const bf16x8*)wf;
    bf16x8 a0 = wfv[(0 * 8 + wv * 2 + 0) * 64 + lane];
    bf16x8 a1 = wfv[(0 * 8 + wv * 2 + 1) * 64 + lane];

    for (int ks = 0; ks < 14; ++ks) {
        bf16x8 na0 = a0, na1 = a1;
        if (ks < 13) {                       // prefetch next A frags
            na0 = wfv[((ks + 1) * 8 + wv * 2 + 0) * 64 + lane];
            na1 = wfv[((ks + 1) * 8 + wv * 2 + 1) * 64 + lane];
        }
        int kof = ks * 32 + quad * 8;
        bf16x8 bb[4];
        #pragma unroll
        for (int nt = 0; nt < 4; ++nt)
            bb[nt] = *(const bf16x8*)(&Bs[(nt * 16 + l16) * BKP + kof]);
        #pragma unroll
        for (int nt = 0; nt < 4; ++nt) {
            acc0[nt] = __builtin_amdgcn_mfma_f32_16x16x32_bf16(a0, bb[nt], acc0[nt], 0, 0, 0);
            acc1[nt] = __builtin_amdgcn_mfma_f32_16x16x32_bf16(a1, bb[nt], acc1[nt], 0, 0, 0);
        }
        a0 = na0; a1 = na1;
    }

    // ---- epilogue: D col = l16 (h), row = quad*4 + r (o within 16-tile)
    float* outb = out + (size_t)b * ((size_t)COUT * HEX);
    #pragma unroll
    for (int nt = 0; nt < 4; ++nt) {
        int h = h0 + nt * 16 + l16;
        if (h >= HEX) continue;
        float s = invtv[h];
        #pragma unroll
        for (int r = 0; r < 4; ++r) {
            int o0 = wv * 32 +  0 + quad * 4 + r;
            int o1 = wv * 32 + 16 + quad * 4 + r;
            outb[(size_t)o0 * HEX + h] = acc0[nt][r] * s + bias[o0];
            outb[(size_t)o1 * HEX + h] = acc1[nt][r] * s + bias[o1];
        }
    }
}

// ---------------------------------------------------------------------------
extern "C" void kernel_launch(void* const* d_in, const int* in_sizes, int n_in,
                              void* d_out, int out_size, void* d_ws, size_t ws_size,
                              hipStream_t stream) {
    const float* x    = (const float*)d_in[0];   // [256][64][1039] fp32
    const int*   nb   = (const int*)d_in[1];     // [1039][6] int32
    const float* wc   = (const float*)d_in[2];   // [128][64] fp32
    const float* wn   = (const float*)d_in[3];   // [128][64][6] fp32
    const float* bias = (const float*)d_in[4];   // [128] fp32
    float*       out  = (float*)d_out;           // [256][128][1039] fp32

    // workspace layout
    const size_t WF_BYTES = (size_t)KDIM * COUT * 2;                 // 114688
    const size_t XT_OFF   = 131072;                                  // 16B-aligned
    const size_t XT_BYTES = (size_t)BATCH * HEX * CIN * 2;           // 34 MB
    unsigned short* wf    = (unsigned short*)d_ws;
    float*          invtv = (float*)((char*)d_ws + WF_BYTES);
    unsigned short* xt    = (unsigned short*)((char*)d_ws + XT_OFF);
    bool big = ws_size >= XT_OFF + XT_BYTES;     // ws_size constant -> graph-safe

    hipLaunchKernelGGL(k_packw, dim3(224), dim3(256), 0, stream, wc, wn, wf);
    hipLaunchKernelGGL(k_invtv, dim3(5),   dim3(256), 0, stream, nb, invtv);
    if (big)
        hipLaunchKernelGGL(k_transpose, dim3(BATCH * NTH), dim3(256), 0, stream, x, xt);
    hipLaunchKernelGGL(k_gemm, dim3(BATCH * NTH), dim3(256), 0, stream,
                       x, big ? xt : (unsigned short*)nullptr, wf, nb, invtv, bias, out);
}

// Round 3
// 284.892 us; speedup vs baseline: 1.2335x; 1.2335x over previous
//
#include <hip/hip_runtime.h>

// Problem constants (ConvHex): B=256, C_IN=64, C_OUT=128, H=1039, K=6
// Dtypes: x, weights, bias, out = fp32; neighbors = int32.
// Compute uses bf16 MFMA; threshold 3.375e-2 covers bf16 rounding (measured 7.8e-3).
#define BATCH 256
#define CIN   64
#define COUT  128
#define HEX   1039
#define KNB   6
#define KDIM  448          // CIN * (KNB + 1)
#define BN    64           // h per block in GEMM
#define NTH   17           // ceil(HEX / BN)
#define BKP   456          // padded LDS row stride (448 + 8), keeps 16B row alignment
#define HROWS (HEX + 1)    // xt rows per batch: +1 zero row at index HEX

typedef __attribute__((ext_vector_type(8))) short bf16x8;   // 8 bf16 = 4 VGPRs
typedef __attribute__((ext_vector_type(4))) float f32x4;

__device__ __forceinline__ unsigned short f2bf(float f) {
    unsigned int u = __builtin_bit_cast(unsigned int, f);
    u += 0x7fffu + ((u >> 16) & 1);          // RTNE
    return (unsigned short)(u >> 16);
}

// ---------------------------------------------------------------------------
// Kernel 1: x[b][c][h] fp32 -> xt[b][h][c] bf16 (+ zero row at h == HEX).
__global__ __launch_bounds__(256) void k_transpose(const float* __restrict__ x,
                                                   unsigned short* __restrict__ xt) {
    __shared__ unsigned short tile[64][65];   // [c][h-in-tile]
    int b  = blockIdx.x / NTH;
    int ht = blockIdx.x % NTH;
    int h0 = ht * 64;
    int tid = threadIdx.x;

    const float* xb = x + (size_t)b * CIN * HEX;
    // read: float4 along h; 64 c-rows x 16 float4 = 1024 loads / 256 thr = 4 each
    int hi4 = (tid & 15) * 4;
    int c0  = tid >> 4;            // 0..15
    for (int cc = c0; cc < 64; cc += 16) {
        int h = h0 + hi4;
        if (h + 3 < HEX) {
            float4 v = *(const float4*)(xb + (size_t)cc * HEX + h);
            tile[cc][hi4 + 0] = f2bf(v.x);
            tile[cc][hi4 + 1] = f2bf(v.y);
            tile[cc][hi4 + 2] = f2bf(v.z);
            tile[cc][hi4 + 3] = f2bf(v.w);
        } else {
            #pragma unroll
            for (int k = 0; k < 4; ++k)
                tile[cc][hi4 + k] = (h + k < HEX) ? f2bf(xb[(size_t)cc * HEX + h + k])
                                                  : (unsigned short)0;
        }
    }
    __syncthreads();

    // write: bf16x8 (16B) per chunk; row h = 8 chunks; h==HEX writes the zero row
    unsigned short* xtb = xt + (size_t)b * HROWS * CIN;
    int c8 = (tid & 7) * 8;
    int hj = tid >> 3;             // 0..31
    for (int hh = hj; hh < 64; hh += 32) {
        int h = h0 + hh;
        if (h <= HEX) {            // row HEX = zeros (tile guard zeroed it)
            bf16x8 v;
            #pragma unroll
            for (int k = 0; k < 8; ++k) v[k] = (short)tile[c8 + k][hh];
            *(bf16x8*)(xtb + (size_t)h * CIN + c8) = v;
        }
    }
}

// ---------------------------------------------------------------------------
// Kernel 2: pack [Wc | Wn] (fp32) into bf16 MFMA A-fragment lane order.
// wf element e = ((kb*8 + mt)*64 + lane)*8 + j :
//   o  = mt*16 + (lane&15)
//   kd = kb*32 + (lane>>4)*8 + j,  kd = jn*64 + c  (jn==0 -> center)
__global__ __launch_bounds__(256) void k_packw(const float* __restrict__ wc,
                                               const float* __restrict__ wn,
                                               unsigned short* __restrict__ wf) {
    int e    = blockIdx.x * 256 + threadIdx.x;   // 0 .. 57343
    int j    = e & 7;
    int lane = (e >> 3) & 63;
    int mt   = (e >> 9) & 7;
    int kb   = e >> 12;                          // 0..13
    int o  = mt * 16 + (lane & 15);
    int kd = kb * 32 + (lane >> 4) * 8 + j;
    int jn = kd >> 6;
    int c  = kd & 63;
    float v = (jn == 0) ? wc[o * CIN + c]
                        : wn[(o * CIN + c) * KNB + (jn - 1)];
    wf[e] = f2bf(v);
}

// ---------------------------------------------------------------------------
// Kernel 3a: inv_tv[h] = 1 / (1 + #valid neighbors)
__global__ __launch_bounds__(256) void k_invtv(const int* __restrict__ nb,
                                               float* __restrict__ invtv) {
    int h = blockIdx.x * 256 + threadIdx.x;
    if (h < HEX) {
        int cnt = 1;
        #pragma unroll
        for (int k = 0; k < KNB; ++k) cnt += (nb[h * KNB + k] >= 0) ? 1 : 0;
        invtv[h] = 1.0f / (float)cnt;
    }
}

// Kernel 3b: dense gather table. gidx[ht*448 + p] = xt row to read for
// (h-tile ht, p = jn*64 + n); invalid/OOB -> HEX (the zero row).
__global__ __launch_bounds__(256) void k_gidx(const int* __restrict__ nb,
                                              int* __restrict__ gidx) {
    int e = blockIdx.x * 256 + threadIdx.x;
    if (e >= NTH * KDIM) return;
    int ht = e / KDIM;
    int p  = e - ht * KDIM;
    int jn = p >> 6;
    int n  = p & 63;
    int h  = ht * 64 + n;
    int g  = HEX;                               // zero row
    if (h < HEX) {
        if (jn == 0) g = h;
        else {
            int t = nb[h * KNB + (jn - 1)];
            if (t >= 0) g = t;
        }
    }
    gidx[e] = g;
}

// ---------------------------------------------------------------------------
// Kernel 4: gathered GEMM. Block = (b, 64-h tile); 8 waves (512 thr).
// Wave wv computes o in [wv*16, wv*16+16) x 64 h (4 n-frags).
// B staged to LDS branch-free via gidx (invalid -> zero row), 1 barrier.
__global__ __launch_bounds__(512) void k_gemm(const unsigned short* __restrict__ xt,
                                              const unsigned short* __restrict__ wf,
                                              const int* __restrict__ gidx,
                                              const float* __restrict__ invtv,
                                              const float* __restrict__ bias,
                                              float* __restrict__ out) {
    __shared__ __align__(16) unsigned short Bs[BN * BKP];   // 58368 B

    int ht = blockIdx.x % NTH;
    int b  = blockIdx.x / NTH;
    int h0 = ht * BN;
    int tid = threadIdx.x;

    // ---- stage B: Bs[n][jn*64 + c] = xt[b][gidx(ht,p)][c]  (branch-free)
    {
        const unsigned short* xtb = xt + (size_t)b * (HROWS * CIN);
        const int* gt = gidx + ht * KDIM;
        int lane8 = tid & 7;                 // 16B chunk within a 128B row
        int p0    = tid >> 3;                // 0..63
        #pragma unroll
        for (int i = 0; i < 7; ++i) {
            int p  = p0 + i * 64;            // p = jn*64 + n
            int g  = gt[p];
            int jn = p >> 6;
            int n  = p & 63;
            bf16x8 v = *(const bf16x8*)(xtb + (size_t)g * CIN + lane8 * 8);
            *(bf16x8*)(&Bs[n * BKP + jn * 64 + lane8 * 8]) = v;
        }
    }
    __syncthreads();

    int wv   = tid >> 6;        // wave 0..7 = m-tile
    int lane = tid & 63;
    int quad = lane >> 4;
    int l16  = lane & 15;

    f32x4 acc[4] = {};          // o = wv*16 + quad*4 + r, 4 n-frags

    const bf16x8* wfv = (const bf16x8*)wf;
    bf16x8 a = wfv[(0 * 8 + wv) * 64 + lane];

    for (int ks = 0; ks < 14; ++ks) {
        bf16x8 na = a;
        if (ks < 13) na = wfv[((ks + 1) * 8 + wv) * 64 + lane];   // prefetch next A
        int kof = ks * 32 + quad * 8;
        #pragma unroll
        for (int nt = 0; nt < 4; ++nt) {
            bf16x8 bb = *(const bf16x8*)(&Bs[(nt * 16 + l16) * BKP + kof]);
            acc[nt] = __builtin_amdgcn_mfma_f32_16x16x32_bf16(a, bb, acc[nt], 0, 0, 0);
        }
        a = na;
    }

    // ---- epilogue: D col = l16 (h), row = quad*4 + r (o within 16-tile)
    float* outb = out + (size_t)b * ((size_t)COUT * HEX);
    #pragma unroll
    for (int nt = 0; nt < 4; ++nt) {
        int h = h0 + nt * 16 + l16;
        if (h >= HEX) continue;
        float s = invtv[h];
        #pragma unroll
        for (int r = 0; r < 4; ++r) {
            int o = wv * 16 + quad * 4 + r;
            outb[(size_t)o * HEX + h] = acc[nt][r] * s + bias[o];
        }
    }
}

// ---------------------------------------------------------------------------
extern "C" void kernel_launch(void* const* d_in, const int* in_sizes, int n_in,
                              void* d_out, int out_size, void* d_ws, size_t ws_size,
                              hipStream_t stream) {
    const float* x    = (const float*)d_in[0];   // [256][64][1039] fp32
    const int*   nb   = (const int*)d_in[1];     // [1039][6] int32
    const float* wc   = (const float*)d_in[2];   // [128][64] fp32
    const float* wn   = (const float*)d_in[3];   // [128][64][6] fp32
    const float* bias = (const float*)d_in[4];   // [128] fp32
    float*       out  = (float*)d_out;           // [256][128][1039] fp32

    // workspace layout
    const size_t WF_BYTES   = (size_t)KDIM * COUT * 2;       // 114688
    const size_t INVTV_OFF  = WF_BYTES;                      // 4156 B
    const size_t GIDX_OFF   = 131072;                        // 17*448*4 = 30464 B
    const size_t XT_OFF     = 196608;                        // 16B-aligned
    unsigned short* wf    = (unsigned short*)d_ws;
    float*          invtv = (float*)((char*)d_ws + INVTV_OFF);
    int*            gidx  = (int*)((char*)d_ws + GIDX_OFF);
    unsigned short* xt    = (unsigned short*)((char*)d_ws + XT_OFF);

    hipLaunchKernelGGL(k_packw,     dim3(224), dim3(256), 0, stream, wc, wn, wf);
    hipLaunchKernelGGL(k_invtv,     dim3(5),   dim3(256), 0, stream, nb, invtv);
    hipLaunchKernelGGL(k_gidx,      dim3((NTH * KDIM + 255) / 256), dim3(256), 0, stream, nb, gidx);
    hipLaunchKernelGGL(k_transpose, dim3(BATCH * NTH), dim3(256), 0, stream, x, xt);
    hipLaunchKernelGGL(k_gemm,      dim3(BATCH * NTH), dim3(512), 0, stream,
                       xt, wf, gidx, invtv, bias, out);
}

// Round 4
// 278.463 us; speedup vs baseline: 1.2620x; 1.0231x over previous
//
#include <hip/hip_runtime.h>

// Problem constants (ConvHex): B=256, C_IN=64, C_OUT=128, H=1039, K=6
// Dtypes: x, weights, bias, out = fp32; neighbors = int32.
// Compute uses bf16 MFMA; threshold 3.375e-2 covers bf16 rounding (measured 7.8e-3).
#define BATCH 256
#define CIN   64
#define COUT  128
#define HEX   1039
#define KNB   6
#define KDIM  448          // CIN * (KNB + 1)
#define BN    64           // h per block in GEMM
#define NTH   17           // ceil(HEX / BN)  (GEMM tiling)
#define THT   32           // h per transpose block
#define NTT   33           // ceil(HEX / THT)
#define BKP   456          // padded LDS row stride (448 + 8), keeps 16B row alignment
#define HROWS (HEX + 1)    // xt rows per batch: +1 zero row at index HEX

typedef __attribute__((ext_vector_type(8))) short bf16x8;   // 8 bf16 = 4 VGPRs
typedef __attribute__((ext_vector_type(4))) float f32x4;

__device__ __forceinline__ unsigned short f2bf(float f) {
    unsigned int u = __builtin_bit_cast(unsigned int, f);
    u += 0x7fffu + ((u >> 16) & 1);          // RTNE
    return (unsigned short)(u >> 16);
}

// ---------------------------------------------------------------------------
// Kernel 1: transpose x[b][c][h] fp32 -> xt[b][h][c] bf16, no LDS.
// Block = (b, 32-h strip). Reads: 8 strided 4B loads/thread; each 128B line
// of x is consumed exactly once within the block (8KB working set -> L1).
// Writes: wave = 8 contiguous 128B bf16 rows, fully coalesced 16B/lane.
__global__ __launch_bounds__(256) void k_transpose(const float* __restrict__ x,
                                                   unsigned short* __restrict__ xt) {
    int b  = blockIdx.x / NTT;
    int ht = blockIdx.x % NTT;
    int h  = ht * THT + (threadIdx.x >> 3);   // 0..31 h-in-strip
    int c8 = (threadIdx.x & 7) * 8;
    if (h >= HEX) return;
    const float* xb = x + (size_t)b * (CIN * HEX) + h;
    bf16x8 v;
    #pragma unroll
    for (int k = 0; k < 8; ++k)
        v[k] = (short)f2bf(xb[(size_t)(c8 + k) * HEX]);
    *(bf16x8*)(xt + (size_t)b * (HROWS * CIN) + (size_t)h * CIN + c8) = v;
}

// ---------------------------------------------------------------------------
// Kernel 2 (fused prep, 260 blocks):
//  blocks 0..223  : pack [Wc|Wn] fp32 -> bf16 MFMA A-fragment lane order
//  blocks 224..228: inv_tv[h] = 1/(1 + #valid neighbors)
//  blocks 229..258: gidx[ht*448+p] = xt row for (ht, p=jn*64+n); invalid -> HEX
//  block  259     : zero row xt[b][HEX][*] for all b
__global__ __launch_bounds__(256) void k_prep(const float* __restrict__ wc,
                                              const float* __restrict__ wn,
                                              const int* __restrict__ nb,
                                              unsigned short* __restrict__ wf,
                                              float* __restrict__ invtv,
                                              int* __restrict__ gidx,
                                              unsigned short* __restrict__ xt) {
    int blk = blockIdx.x;
    int tid = threadIdx.x;
    if (blk < 224) {
        // wf element e = ((kb*8 + mt)*64 + lane)*8 + j :
        //   o = mt*16 + (lane&15); kd = kb*32 + (lane>>4)*8 + j = jn*64 + c
        int e    = blk * 256 + tid;              // 0 .. 57343
        int j    = e & 7;
        int lane = (e >> 3) & 63;
        int mt   = (e >> 9) & 7;
        int kb   = e >> 12;                      // 0..13
        int o  = mt * 16 + (lane & 15);
        int kd = kb * 32 + (lane >> 4) * 8 + j;
        int jn = kd >> 6;
        int c  = kd & 63;
        float v = (jn == 0) ? wc[o * CIN + c]
                            : wn[(o * CIN + c) * KNB + (jn - 1)];
        wf[e] = f2bf(v);
    } else if (blk < 229) {
        int h = (blk - 224) * 256 + tid;
        if (h < HEX) {
            int cnt = 1;
            #pragma unroll
            for (int k = 0; k < KNB; ++k) cnt += (nb[h * KNB + k] >= 0) ? 1 : 0;
            invtv[h] = 1.0f / (float)cnt;
        }
    } else if (blk < 259) {
        int e = (blk - 229) * 256 + tid;
        if (e < NTH * KDIM) {
            int ht = e / KDIM;
            int p  = e - ht * KDIM;
            int jn = p >> 6;
            int n  = p & 63;
            int h  = ht * 64 + n;
            int g  = HEX;                        // zero row
            if (h < HEX) {
                if (jn == 0) g = h;
                else {
                    int t = nb[h * KNB + (jn - 1)];
                    if (t >= 0) g = t;
                }
            }
            gidx[e] = g;
        }
    } else {
        // zero row per batch: xt[b][HEX][0..63] = 0   (256 b x 128 B)
        int b = tid;                             // 256 threads = 256 batches
        bf16x8 z = {};
        unsigned short* row = xt + (size_t)b * (HROWS * CIN) + (size_t)HEX * CIN;
        #pragma unroll
        for (int k = 0; k < 8; ++k)
            *(bf16x8*)(row + k * 8) = z;
    }
}

// ---------------------------------------------------------------------------
// Kernel 3: gathered GEMM. Block = (b, 64-h tile); 8 waves (512 thr).
// Wave wv computes o in [wv*16, wv*16+16) x 64 h (4 n-frags).
// B staged to LDS branch-free via gidx (invalid -> zero row), 1 barrier.
__global__ __launch_bounds__(512) void k_gemm(const unsigned short* __restrict__ xt,
                                              const unsigned short* __restrict__ wf,
                                              const int* __restrict__ gidx,
                                              const float* __restrict__ invtv,
                                              const float* __restrict__ bias,
                                              float* __restrict__ out) {
    __shared__ __align__(16) unsigned short Bs[BN * BKP];   // 58368 B -> 2 blocks/CU

    int ht = blockIdx.x % NTH;
    int b  = blockIdx.x / NTH;
    int h0 = ht * BN;
    int tid = threadIdx.x;

    // ---- stage B: Bs[n][jn*64 + c] = xt[b][gidx(ht,p)][c]  (branch-free)
    {
        const unsigned short* xtb = xt + (size_t)b * (HROWS * CIN);
        const int* gt = gidx + ht * KDIM;
        int lane8 = tid & 7;                 // 16B chunk within a 128B row
        int p0    = tid >> 3;                // 0..63
        int gs[7];
        #pragma unroll
        for (int i = 0; i < 7; ++i)          // issue all 7 index loads first
            gs[i] = gt[p0 + i * 64];
        #pragma unroll
        for (int i = 0; i < 7; ++i) {
            int p  = p0 + i * 64;            // p = jn*64 + n
            int jn = p >> 6;
            int n  = p & 63;
            bf16x8 v = *(const bf16x8*)(xtb + (size_t)gs[i] * CIN + lane8 * 8);
            *(bf16x8*)(&Bs[n * BKP + jn * 64 + lane8 * 8]) = v;
        }
    }
    __syncthreads();

    int wv   = tid >> 6;        // wave 0..7 = m-tile
    int lane = tid & 63;
    int quad = lane >> 4;
    int l16  = lane & 15;

    f32x4 acc[4] = {};          // o = wv*16 + quad*4 + r, 4 n-frags

    const bf16x8* wfv = (const bf16x8*)wf;
    bf16x8 a = wfv[(0 * 8 + wv) * 64 + lane];

    for (int ks = 0; ks < 14; ++ks) {
        bf16x8 na = a;
        if (ks < 13) na = wfv[((ks + 1) * 8 + wv) * 64 + lane];   // prefetch next A
        int kof = ks * 32 + quad * 8;
        #pragma unroll
        for (int nt = 0; nt < 4; ++nt) {
            bf16x8 bb = *(const bf16x8*)(&Bs[(nt * 16 + l16) * BKP + kof]);
            acc[nt] = __builtin_amdgcn_mfma_f32_16x16x32_bf16(a, bb, acc[nt], 0, 0, 0);
        }
        a = na;
    }

    // ---- epilogue: D col = l16 (h), row = quad*4 + r (o within 16-tile)
    float* outb = out + (size_t)b * ((size_t)COUT * HEX);
    #pragma unroll
    for (int nt = 0; nt < 4; ++nt) {
        int h = h0 + nt * 16 + l16;
        if (h >= HEX) continue;
        float s = invtv[h];
        #pragma unroll
        for (int r = 0; r < 4; ++r) {
            int o = wv * 16 + quad * 4 + r;
            outb[(size_t)o * HEX + h] = acc[nt][r] * s + bias[o];
        }
    }
}

// ---------------------------------------------------------------------------
extern "C" void kernel_launch(void* const* d_in, const int* in_sizes, int n_in,
                              void* d_out, int out_size, void* d_ws, size_t ws_size,
                              hipStream_t stream) {
    const float* x    = (const float*)d_in[0];   // [256][64][1039] fp32
    const int*   nb   = (const int*)d_in[1];     // [1039][6] int32
    const float* wc   = (const float*)d_in[2];   // [128][64] fp32
    const float* wn   = (const float*)d_in[3];   // [128][64][6] fp32
    const float* bias = (const float*)d_in[4];   // [128] fp32
    float*       out  = (float*)d_out;           // [256][128][1039] fp32

    // workspace layout (ws_size ~545 MB per harness fill; we use ~34.3 MB)
    const size_t INVTV_OFF = (size_t)KDIM * COUT * 2;        // 114688
    const size_t GIDX_OFF  = 131072;                         // 17*448*4 = 30464 B
    const size_t XT_OFF    = 196608;                         // 16B-aligned
    unsigned short* wf    = (unsigned short*)d_ws;
    float*          invtv = (float*)((char*)d_ws + INVTV_OFF);
    int*            gidx  = (int*)((char*)d_ws + GIDX_OFF);
    unsigned short* xt    = (unsigned short*)((char*)d_ws + XT_OFF);

    hipLaunchKernelGGL(k_prep,      dim3(260),         dim3(256), 0, stream,
                       wc, wn, nb, wf, invtv, gidx, xt);
    hipLaunchKernelGGL(k_transpose, dim3(BATCH * NTT), dim3(256), 0, stream, x, xt);
    hipLaunchKernelGGL(k_gemm,      dim3(BATCH * NTH), dim3(512), 0, stream,
                       xt, wf, gidx, invtv, bias, out);
}